// Round 7
// baseline (111.038 us; speedup 1.0000x reference)
//
#include <hip/hip_runtime.h>
#include <math.h>

#define NQ 22
#define NH 9        // high qubits 0..8   (h = x >> 13)
#define NL 13       // low qubits 9..21   (l = x & 8191)
#define HD 512
#define LD 8192
#define RS 8224     // state row stride in floats (odd multiple of 128 B line)

// In-register butterfly over register-index bit K (32 regs -> 16 pairs).
template<int K>
__device__ __forceinline__ void bfly32(float v[32], float2 cc) {
    const float c = cc.x, s = cc.y;
#pragma unroll
    for (int p = 0; p < 16; ++p) {
        int i0 = ((p >> K) << (K + 1)) | (p & ((1 << K) - 1));
        int i1 = i0 | (1 << K);
        float a = v[i0], b = v[i1];
        v[i0] = c * a - s * b;
        v[i1] = s * a + c * b;
    }
}

// ---------------- kA: init (feat+p0+sign analytic) + layer-1 low ----------
// No precomputed tables: per-block GF2-linear decomposition.
//   init(h,l) = whs * A6[l&63] * A7[l>>6] * (-1)^popc(l6 & CM[h7])
// Mappings (l within the 8192-chunk of row h), thread t, reg r:
//   A : l = r + 32*t                 (reg bits = l bits 0-4, qubits 21..17)
//   B : l = (t&31)+32*r+1024*(t>>5)  (reg bits = l bits 5-9, qubits 16..12)
//   C': l = 4*t + (r&3) + 1024*(r>>2)(reg bits 2-4 = l bits 10-12, qubits 11..9)
// LDS layout f(l) = l + (l>>5). launch_bounds(256,4): v[32] must not spill (R2).
__global__ __launch_bounds__(256, 4) void kA(float* state, const float* feat,
                                             const float* adj, const float* params) {
    __shared__ float chunk[8448];
    __shared__ float A6[64];
    __shared__ float A7[128];
    __shared__ unsigned CM[128];
    __shared__ float2 cs0[NQ];     // half-angle (feat+params0) cos/sin, all qubits
    __shared__ float2 csl[13];     // layer-1 low rotations; csl[qi] = qubit 9+qi
    __shared__ unsigned cm9[13];   // high-adjacency mask of low qubit qi (9-bit)
    __shared__ unsigned llm[13];   // strict low-low masks (13-bit, bit 12-qj)
    __shared__ unsigned hm[9];     // strict high-high masks (9-bit, bit 8-j2)
    __shared__ float whs_s;
    const int h = blockIdx.x, t = threadIdx.x;

    if (t < NQ) {
        float a = 0.5f * (feat[t] + params[t]);
        cs0[t] = make_float2(cosf(a), sinf(a));
    } else if (t < NQ + 13) {
        int qi = t - NQ;
        float a = 0.5f * params[NQ + 9 + qi];
        csl[qi] = make_float2(cosf(a), sinf(a));
    } else if (t < NQ + 26) {
        int qi = t - NQ - 13;
        unsigned m = 0;
        for (int i = 0; i < 9; ++i) if (adj[i * NQ + 9 + qi] > 0.f) m |= 1u << (8 - i);
        cm9[qi] = m;
    } else if (t < NQ + 39) {
        int qi = t - NQ - 26;
        unsigned m = 0;
        for (int qj = qi + 1; qj < 13; ++qj)
            if (adj[(9 + qi) * NQ + 9 + qj] > 0.f) m |= 1u << (12 - qj);
        llm[qi] = m;
    } else if (t < NQ + 48) {
        int i = t - NQ - 39;
        unsigned m = 0;
        for (int j2 = i + 1; j2 < 9; ++j2)
            if (adj[i * NQ + j2] > 0.f) m |= 1u << (8 - j2);
        hm[i] = m;
    }
    __syncthreads();
    if (t == 0) {   // w[h], sigh[h]
        float w = 1.f; unsigned sg = 0;
        for (int i = 0; i < 9; ++i) {
            int bit = (h >> (8 - i)) & 1;
            w *= bit ? cs0[i].y : cs0[i].x;
            sg ^= (unsigned)(bit & (__popc(h & hm[i]) & 1));
        }
        whs_s = sg ? -w : w;
    }
    if (t < 64) {          // A6: qubits 21..16 (l6 bit k <-> qubit 21-k, qi=12-k)
        int l6 = t; float p = 1.f; unsigned sn = 0;
        for (int k = 0; k < 6; ++k) {
            int bit = (l6 >> k) & 1;
            p *= bit ? cs0[21 - k].y : cs0[21 - k].x;
            sn ^= (unsigned)(bit & ((__popc(l6 & (llm[12 - k] & 63u)) ^
                                     __popc(h & cm9[12 - k])) & 1));
        }
        A6[l6] = sn ? -p : p;
    } else if (t < 192) {  // A7+CM: qubits 15..9 (h7 bit k <-> qubit 15-k, qi=6-k)
        int h7 = t - 64; float p = 1.f; unsigned sn = 0, cm = 0;
        for (int k = 0; k < 7; ++k) {
            int bit = (h7 >> k) & 1;
            p *= bit ? cs0[15 - k].y : cs0[15 - k].x;
            sn ^= (unsigned)(bit & ((__popc(h7 & (llm[6 - k] >> 6)) ^
                                     __popc(h & cm9[6 - k])) & 1));
            if (bit) cm ^= llm[6 - k] & 63u;
        }
        A7[h7] = sn ? -p : p;
        CM[h7] = cm;
    }
    __syncthreads();

    float v[32];
    {   // mapping A: l = r + 32t -> l6 = 32(t&1)+r, h7 = t>>1
        const int h7 = t >> 1, base = (t & 1) * 32;
        const float a7 = A7[h7] * whs_s;
        const unsigned cm = CM[h7];
#pragma unroll
        for (int r = 0; r < 32; ++r) {
            int l6 = base + r;
            float val = A6[l6] * a7;
            v[r] = (__popc(l6 & cm) & 1) ? -val : val;
        }
    }
    // A stages: qubits 21..17 -> csl[12..8]
    bfly32<0>(v, csl[12]); bfly32<1>(v, csl[11]); bfly32<2>(v, csl[10]);
    bfly32<3>(v, csl[9]);  bfly32<4>(v, csl[8]);

#pragma unroll
    for (int r = 0; r < 32; ++r) chunk[r + 33 * t] = v[r];
    __syncthreads();
    const int t5 = t & 31, th = t >> 5;
#pragma unroll
    for (int r = 0; r < 32; ++r) v[r] = chunk[t5 + 33 * r + 1056 * th];  // mapping B

    // B stages: qubits 16..12 -> csl[7..3]
    bfly32<0>(v, csl[7]); bfly32<1>(v, csl[6]); bfly32<2>(v, csl[5]);
    bfly32<3>(v, csl[4]); bfly32<4>(v, csl[3]);

    __syncthreads();
#pragma unroll
    for (int r = 0; r < 32; ++r) chunk[t5 + 33 * r + 1056 * th] = v[r];
    __syncthreads();
#pragma unroll
    for (int r = 0; r < 32; ++r) {
        int l = 4 * t + (r & 3) + 1024 * (r >> 2);                  // mapping C'
        v[r] = chunk[l + (l >> 5)];
    }

    // C' stages: qubits 11,10,9 -> csl[2],csl[1],csl[0]
    bfly32<2>(v, csl[2]); bfly32<3>(v, csl[1]); bfly32<4>(v, csl[0]);

    float4* sp = (float4*)(state + (size_t)h * RS + 4 * t);
#pragma unroll
    for (int r5 = 0; r5 < 8; ++r5)
        sp[r5 * 256] = make_float4(v[4*r5], v[4*r5+1], v[4*r5+2], v[4*r5+3]);
}

// ---------------- kB: layer-1 high + sign + layer-2 high (fused column pass) ----------
// beta : m = (r&15) + 16*g + 256*(r>>4)  (reg bits = m bits {0,1,2,3,8})
// alpha: m = g + 16*r                    (reg bits = m bits 4-8)
// Tables built in-kernel; also zeroes out[] (runs before kC).
__global__ __launch_bounds__(256, 4) void kB(float* state, const float* adj,
                                             const float* params, float* out) {
    __shared__ float tile[8704];
    __shared__ unsigned sgh[HD];
    __shared__ float2 c1h[9], c2h[9];
    __shared__ unsigned lvs[16];
    __shared__ unsigned hm[9];
    __shared__ unsigned cm9[13];
    __shared__ unsigned llm[13];
    const int t = threadIdx.x;
    const int j = t & 15, g = t >> 4;
    const int b = blockIdx.x;
    const int rb = ((b & 7) * 64 + (b >> 3)) * 16;   // XCD-swizzled column base

    if (b == 0 && t < NQ) out[t] = 0.f;              // kC accumulates atomically

    // issue global loads early (independent of LDS table work)
    float v[32];
    const float* gp = state + rb + j;
#pragma unroll
    for (int r = 0; r < 32; ++r) {
        int m = (r & 15) + 16 * g + 256 * (r >> 4);
        v[r] = gp[(size_t)m * RS];
    }

    if (t < 9) {
        unsigned m = 0;
        for (int j2 = t + 1; j2 < 9; ++j2)
            if (adj[t * NQ + j2] > 0.f) m |= 1u << (8 - j2);
        hm[t] = m;
    } else if (t >= 16 && t < 34) {
        int i = t - 16;
        float a = (i < 9) ? 0.5f * params[NQ + i] : 0.5f * params[2 * NQ + (i - 9)];
        float2 cc = make_float2(cosf(a), sinf(a));
        if (i < 9) c1h[i] = cc; else c2h[i - 9] = cc;
    } else if (t >= 34 && t < 47) {
        int qi = t - 34;
        unsigned m = 0;
        for (int i = 0; i < 9; ++i) if (adj[i * NQ + 9 + qi] > 0.f) m |= 1u << (8 - i);
        cm9[qi] = m;
    } else if (t >= 47 && t < 60) {
        int qi = t - 47;
        unsigned m = 0;
        for (int qj = qi + 1; qj < 13; ++qj)
            if (adj[(9 + qi) * NQ + 9 + qj] > 0.f) m |= 1u << (12 - qj);
        llm[qi] = m;
    }
    __syncthreads();
    {   // sgh[512]
        for (int hh = t; hh < HD; hh += 256) {
            unsigned sg = 0;
            for (int i = 0; i < 9; ++i) {
                int bit = (hh >> (8 - i)) & 1;
                sg ^= (unsigned)(bit & (__popc(hh & hm[i]) & 1));
            }
            sgh[hh] = sg;
        }
    }
    if (t < 16) {   // lv for this block's 16 columns
        int l = rb + t;
        unsigned V = 0, sl = 0;
        for (int qi = 0; qi < 13; ++qi) {
            int bit = (l >> (12 - qi)) & 1;
            if (bit) V ^= cm9[qi];
            sl ^= (unsigned)(bit & (__popc(l & llm[qi]) & 1));
        }
        lvs[t] = V | (sl << NH);
    }

    // layer-1 high, qubits 8..5 = m bits 0..3 = reg bits 0..3
    bfly32<0>(v, c1h[8]); bfly32<1>(v, c1h[7]); bfly32<2>(v, c1h[6]); bfly32<3>(v, c1h[5]);

    __syncthreads();   // orders sgh/lvs writes and tile writes
#pragma unroll
    for (int r = 0; r < 32; ++r) {
        int m = (r & 15) + 16 * g + 256 * (r >> 4);
        tile[m * 17 + j] = v[r];
    }
    __syncthreads();
#pragma unroll
    for (int r = 0; r < 32; ++r) v[r] = tile[(g + 16 * r) * 17 + j];   // alpha

    // layer-1 high, qubits 4..0 = m bits 4..8 = reg bits 0..4
    bfly32<0>(v, c1h[4]); bfly32<1>(v, c1h[3]); bfly32<2>(v, c1h[2]);
    bfly32<3>(v, c1h[1]); bfly32<4>(v, c1h[0]);

    {   // sign between layers
        unsigned lv = lvs[j];
        unsigned V = lv & 511u, sl = (lv >> NH) & 1u;
#pragma unroll
        for (int r = 0; r < 32; ++r) {
            int m = g + 16 * r;
            unsigned sgn = (sgh[m] ^ sl ^ (unsigned)__popc((unsigned)m & V)) & 1u;
            if (sgn) v[r] = -v[r];
        }
    }

    // layer-2 high, alpha part
    bfly32<0>(v, c2h[4]); bfly32<1>(v, c2h[3]); bfly32<2>(v, c2h[2]);
    bfly32<3>(v, c2h[1]); bfly32<4>(v, c2h[0]);

    __syncthreads();
#pragma unroll
    for (int r = 0; r < 32; ++r) tile[(g + 16 * r) * 17 + j] = v[r];
    __syncthreads();
#pragma unroll
    for (int r = 0; r < 32; ++r) {
        int m = (r & 15) + 16 * g + 256 * (r >> 4);
        v[r] = tile[m * 17 + j];                                       // beta
    }
    // layer-2 high, beta part
    bfly32<0>(v, c2h[8]); bfly32<1>(v, c2h[7]); bfly32<2>(v, c2h[6]); bfly32<3>(v, c2h[5]);

    float* op = state + rb + j;
#pragma unroll
    for (int r = 0; r < 32; ++r) {
        int m = (r & 15) + 16 * g + 256 * (r >> 4);
        op[(size_t)m * RS] = v[r];
    }
}

// ---------------- kC: layer-2 low + probs + 22 expectation partials ----------
__global__ __launch_bounds__(256, 4) void kC(const float* state, const float* params,
                                             float* out) {
    __shared__ float chunk[8448];
    __shared__ float2 csl2[13];    // layer-2 low rotations; csl2[qi] = qubit 9+qi
    const int h = blockIdx.x, t = threadIdx.x;

    if (t < 13) {
        float a = 0.5f * params[2 * NQ + 9 + t];
        csl2[t] = make_float2(cosf(a), sinf(a));
    }

    float v[32];
    const float4* sp = (const float4*)(state + (size_t)h * RS + 4 * t);
#pragma unroll
    for (int r5 = 0; r5 < 8; ++r5) {
        float4 x = sp[r5 * 256];
        v[4*r5] = x.x; v[4*r5+1] = x.y; v[4*r5+2] = x.z; v[4*r5+3] = x.w;  // C'
    }
    __syncthreads();   // csl2 ready

    // C' stages: qubits 11,10,9 -> csl2[2],csl2[1],csl2[0]
    bfly32<2>(v, csl2[2]); bfly32<3>(v, csl2[1]); bfly32<4>(v, csl2[0]);

#pragma unroll
    for (int r = 0; r < 32; ++r) {
        int l = 4 * t + (r & 3) + 1024 * (r >> 2);
        chunk[l + (l >> 5)] = v[r];
    }
    __syncthreads();
    const int t5 = t & 31, th = t >> 5;
#pragma unroll
    for (int r = 0; r < 32; ++r) v[r] = chunk[t5 + 33 * r + 1056 * th];  // B

    // B stages: qubits 16..12 -> csl2[7..3]
    bfly32<0>(v, csl2[7]); bfly32<1>(v, csl2[6]); bfly32<2>(v, csl2[5]);
    bfly32<3>(v, csl2[4]); bfly32<4>(v, csl2[3]);

    __syncthreads();
#pragma unroll
    for (int r = 0; r < 32; ++r) chunk[t5 + 33 * r + 1056 * th] = v[r];
    __syncthreads();
#pragma unroll
    for (int r = 0; r < 32; ++r) v[r] = chunk[r + 33 * t];               // A: l = r + 32t

    // A stages: qubits 21..17 -> csl2[12..8]
    bfly32<0>(v, csl2[12]); bfly32<1>(v, csl2[11]); bfly32<2>(v, csl2[10]);
    bfly32<3>(v, csl2[9]);  bfly32<4>(v, csl2[8]);

    // probs + per-thread partials
#pragma unroll
    for (int r = 0; r < 32; ++r) v[r] = v[r] * v[r];
    float tot = 0.f;
#pragma unroll
    for (int r = 0; r < 32; ++r) tot += v[r];
    float s5[5];
#pragma unroll
    for (int k = 0; k < 5; ++k) {
        float a = 0.f;
#pragma unroll
        for (int r = 0; r < 32; ++r) a += ((r >> k) & 1) ? -v[r] : v[r];
        s5[k] = a;
    }

    // low-pressure LDS reduction, then one atomic per qubit (22 parallel lanes)
    __syncthreads();
    chunk[t] = tot;
#pragma unroll
    for (int k = 0; k < 5; ++k) chunk[256 + k * 256 + t] = s5[k];
    __syncthreads();

    if (t < NQ) {
        const int q = t;
        float val = 0.f;
        if (q < 9) {                       // h bit (8-q), uniform sign over block
            for (int tt = 0; tt < 256; ++tt) val += chunk[tt];
            if ((h >> (8 - q)) & 1) val = -val;
        } else if (q < 17) {               // t-bit i = 16-q of tot
            const int i = 16 - q;
            for (int tt = 0; tt < 256; ++tt)
                val += ((tt >> i) & 1) ? -chunk[tt] : chunk[tt];
        } else {                           // reg bit k = 21-q
            const int k = 21 - q;
            for (int tt = 0; tt < 256; ++tt) val += chunk[256 + k * 256 + tt];
        }
        atomicAdd(&out[q], val);
    }
}

extern "C" void kernel_launch(void* const* d_in, const int* in_sizes, int n_in,
                              void* d_out, int out_size, void* d_ws, size_t ws_size,
                              hipStream_t stream) {
    const float* feat   = (const float*)d_in[0];   // 22
    const float* adj    = (const float*)d_in[1];   // 22*22
    const float* params = (const float*)d_in[2];   // 3*22
    float* out = (float*)d_out;                    // 22 f32

    float* state = (float*)d_ws;                   // 512*8224 floats ~ 16.05 MB

    kA<<<dim3(512), dim3(256), 0, stream>>>(state, feat, adj, params);
    kB<<<dim3(512), dim3(256), 0, stream>>>(state, adj, params, out);
    kC<<<dim3(512), dim3(256), 0, stream>>>(state, params, out);
}

// Round 8
// 103.167 us; speedup vs baseline: 1.0763x; 1.0763x over previous
//
#include <hip/hip_runtime.h>
#include <math.h>

#define NQ 22
#define NH 9        // high qubits 0..8   (h = x >> 13)
#define NL 13       // low qubits 9..21   (l = x & 8191)
#define HD 512
#define LD 8192
#define RS 8224     // state row stride in floats (odd multiple of 128 B line)

// In-register butterfly over register-index bit K (16 regs -> 8 pairs).
template<int K>
__device__ __forceinline__ void bfly16(float v[16], float2 cc) {
    const float c = cc.x, s = cc.y;
#pragma unroll
    for (int p = 0; p < 8; ++p) {
        int i0 = ((p >> K) << (K + 1)) | (p & ((1 << K) - 1));
        int i1 = i0 | (1 << K);
        float a = v[i0], b = v[i1];
        v[i0] = c * a - s * b;
        v[i1] = s * a + c * b;
    }
}

// Cross-lane butterfly over lane-bit `mask` (element bit = lane bit).
// bit = this lane's value of that bit. a'=c*a-s*b (bit0), b'=s*a+c*b (bit1).
__device__ __forceinline__ void bflyx(float v[16], float2 cc, int mask, int bit) {
    const float c = cc.x, s = cc.y;
#pragma unroll
    for (int r = 0; r < 16; ++r) {
        float o = __shfl_xor(v[r], mask, 64);
        v[r] = bit ? (c * v[r] + s * o) : (c * v[r] - s * o);
    }
}

// ---------------- kA: init (feat+p0+sign analytic) + layer-1 low ----------
// 512 threads x 16 regs, one 8192-row per block. Mappings (l in chunk):
//   A : l = r + 16*t            (reg=bits0-3 q21-18; q17 = lane bit0, shfl)
//   B : l = (t&31)+32*r+512*(t>>5) (reg=bits5-8 q16-13)
//   C : l = t + 512*r           (reg=bits9-12 q12-9)
// LDS f(l)=l+(l>>5): A base 16t+(t>>1)+r (contig 16); B t5+33r+528th; C t+(t>>5)+528r.
// launch_bounds(512,4): 16 waves/CU (2 blocks/CU), VGPR cap 128 (v[16] no spill).
__global__ __launch_bounds__(512, 4) void kA(float* state, const float* feat,
                                             const float* adj, const float* params) {
    __shared__ float chunk[8448];
    __shared__ float A6[64];
    __shared__ float A7[128];
    __shared__ unsigned CM[128];
    __shared__ float2 cs0[NQ];
    __shared__ float2 csl[13];     // layer-1 low; csl[qi] = qubit 9+qi
    __shared__ unsigned cm9[13];
    __shared__ unsigned llm[13];
    __shared__ unsigned hm[9];
    __shared__ float whs_s;
    const int h = blockIdx.x, t = threadIdx.x;

    if (t < NQ) {
        float a = 0.5f * (feat[t] + params[t]);
        cs0[t] = make_float2(cosf(a), sinf(a));
    } else if (t < NQ + 13) {
        int qi = t - NQ;
        float a = 0.5f * params[NQ + 9 + qi];
        csl[qi] = make_float2(cosf(a), sinf(a));
    } else if (t < NQ + 26) {
        int qi = t - NQ - 13;
        unsigned m = 0;
        for (int i = 0; i < 9; ++i) if (adj[i * NQ + 9 + qi] > 0.f) m |= 1u << (8 - i);
        cm9[qi] = m;
    } else if (t < NQ + 39) {
        int qi = t - NQ - 26;
        unsigned m = 0;
        for (int qj = qi + 1; qj < 13; ++qj)
            if (adj[(9 + qi) * NQ + 9 + qj] > 0.f) m |= 1u << (12 - qj);
        llm[qi] = m;
    } else if (t < NQ + 48) {
        int i = t - NQ - 39;
        unsigned m = 0;
        for (int j2 = i + 1; j2 < 9; ++j2)
            if (adj[i * NQ + j2] > 0.f) m |= 1u << (8 - j2);
        hm[i] = m;
    }
    __syncthreads();
    if (t == 0) {
        float w = 1.f; unsigned sg = 0;
        for (int i = 0; i < 9; ++i) {
            int bit = (h >> (8 - i)) & 1;
            w *= bit ? cs0[i].y : cs0[i].x;
            sg ^= (unsigned)(bit & (__popc(h & hm[i]) & 1));
        }
        whs_s = sg ? -w : w;
    }
    if (t < 64) {          // A6: qubits 21..16 (l6 bit k <-> qubit 21-k, qi=12-k)
        int l6 = t; float p = 1.f; unsigned sn = 0;
        for (int k = 0; k < 6; ++k) {
            int bit = (l6 >> k) & 1;
            p *= bit ? cs0[21 - k].y : cs0[21 - k].x;
            sn ^= (unsigned)(bit & ((__popc(l6 & (llm[12 - k] & 63u)) ^
                                     __popc(h & cm9[12 - k])) & 1));
        }
        A6[l6] = sn ? -p : p;
    } else if (t < 192) {  // A7+CM: qubits 15..9 (h7 bit k <-> qubit 15-k, qi=6-k)
        int h7 = t - 64; float p = 1.f; unsigned sn = 0, cm = 0;
        for (int k = 0; k < 7; ++k) {
            int bit = (h7 >> k) & 1;
            p *= bit ? cs0[15 - k].y : cs0[15 - k].x;
            sn ^= (unsigned)(bit & ((__popc(h7 & (llm[6 - k] >> 6)) ^
                                     __popc(h & cm9[6 - k])) & 1));
            if (bit) cm ^= llm[6 - k] & 63u;
        }
        A7[h7] = sn ? -p : p;
        CM[h7] = cm;
    }
    __syncthreads();

    float v[16];
    {   // mapping A: l = r + 16t -> l6 = r + 16*(t&3), h7 = t>>2
        const int h7 = t >> 2, l6b = 16 * (t & 3);
        const float a7 = A7[h7] * whs_s;
        const unsigned cm = CM[h7];
#pragma unroll
        for (int r = 0; r < 16; ++r) {
            int l6 = l6b + r;
            float val = A6[l6] * a7;
            v[r] = (__popc(l6 & cm) & 1) ? -val : val;
        }
    }
    // A stages: q21-18 in regs, q17 via lane bit 0
    bfly16<0>(v, csl[12]); bfly16<1>(v, csl[11]); bfly16<2>(v, csl[10]); bfly16<3>(v, csl[9]);
    bflyx(v, csl[8], 1, t & 1);

    const int baseA = 16 * t + (t >> 1);
#pragma unroll
    for (int r = 0; r < 16; ++r) chunk[baseA + r] = v[r];
    __syncthreads();
    const int t5 = t & 31, th = t >> 5;
    const int baseB = t5 + 528 * th;
#pragma unroll
    for (int r = 0; r < 16; ++r) v[r] = chunk[baseB + 33 * r];     // mapping B

    bfly16<0>(v, csl[7]); bfly16<1>(v, csl[6]); bfly16<2>(v, csl[5]); bfly16<3>(v, csl[4]);

    __syncthreads();
#pragma unroll
    for (int r = 0; r < 16; ++r) chunk[baseB + 33 * r] = v[r];
    __syncthreads();
    const int baseC = t + (t >> 5);
#pragma unroll
    for (int r = 0; r < 16; ++r) v[r] = chunk[baseC + 528 * r];    // mapping C

    bfly16<0>(v, csl[3]); bfly16<1>(v, csl[2]); bfly16<2>(v, csl[1]); bfly16<3>(v, csl[0]);

    float* sp = state + (size_t)h * RS + t;                        // store C mapping
#pragma unroll
    for (int r = 0; r < 16; ++r) sp[512 * r] = v[r];
}

// ---------------- kB: layer-1 high + sign + layer-2 high (column pass) ----------
// 512 threads x 16 regs, 16 cols x 512 rows per block. j=t&15, g=t>>4 (0..31).
//   beta : m = r + 16*g   (reg=m bits0-3 q8-5; q4 = lane bit4, shfl)
//   alpha: m = g + 32*r   (reg=m bits5-8 q3-0)
// tile[m*17+j]: beta 2-way, alpha ~2-way: free.
__global__ __launch_bounds__(512, 4) void kB(float* state, const float* adj,
                                             const float* params, float* out) {
    __shared__ float tile[8704];
    __shared__ unsigned sgh[HD];
    __shared__ float2 c1h[9], c2h[9];
    __shared__ unsigned lvs[16];
    __shared__ unsigned hm[9];
    __shared__ unsigned cm9[13];
    __shared__ unsigned llm[13];
    const int t = threadIdx.x;
    const int j = t & 15, g = t >> 4;
    const int b = blockIdx.x;
    const int rb = ((b & 7) * 64 + (b >> 3)) * 16;   // XCD-swizzled column base

    if (b == 0 && t < NQ) out[t] = 0.f;              // kC accumulates atomically

    // issue global loads early
    float v[16];
    const float* gp = state + rb + j;
#pragma unroll
    for (int r = 0; r < 16; ++r) v[r] = gp[(size_t)(r + 16 * g) * RS];   // beta

    if (t < 9) {
        unsigned m = 0;
        for (int j2 = t + 1; j2 < 9; ++j2)
            if (adj[t * NQ + j2] > 0.f) m |= 1u << (8 - j2);
        hm[t] = m;
    } else if (t >= 16 && t < 34) {
        int i = t - 16;
        float a = (i < 9) ? 0.5f * params[NQ + i] : 0.5f * params[2 * NQ + (i - 9)];
        float2 cc = make_float2(cosf(a), sinf(a));
        if (i < 9) c1h[i] = cc; else c2h[i - 9] = cc;
    } else if (t >= 34 && t < 47) {
        int qi = t - 34;
        unsigned m = 0;
        for (int i = 0; i < 9; ++i) if (adj[i * NQ + 9 + qi] > 0.f) m |= 1u << (8 - i);
        cm9[qi] = m;
    } else if (t >= 47 && t < 60) {
        int qi = t - 47;
        unsigned m = 0;
        for (int qj = qi + 1; qj < 13; ++qj)
            if (adj[(9 + qi) * NQ + 9 + qj] > 0.f) m |= 1u << (12 - qj);
        llm[qi] = m;
    }
    __syncthreads();
    {   // sgh[512]: one entry per thread
        unsigned sg = 0;
        for (int i = 0; i < 9; ++i) {
            int bit = (t >> (8 - i)) & 1;
            sg ^= (unsigned)(bit & (__popc(t & hm[i]) & 1));
        }
        sgh[t] = sg;
    }
    if (t < 16) {   // lv for this block's 16 columns
        int l = rb + t;
        unsigned V = 0, sl = 0;
        for (int qi = 0; qi < 13; ++qi) {
            int bit = (l >> (12 - qi)) & 1;
            if (bit) V ^= cm9[qi];
            sl ^= (unsigned)(bit & (__popc(l & llm[qi]) & 1));
        }
        lvs[t] = V | (sl << NH);
    }

    // layer-1 high: beta q8-5 in regs, q4 via lane bit 4
    bfly16<0>(v, c1h[8]); bfly16<1>(v, c1h[7]); bfly16<2>(v, c1h[6]); bfly16<3>(v, c1h[5]);
    bflyx(v, c1h[4], 16, g & 1);

    __syncthreads();   // orders sgh/lvs writes too
#pragma unroll
    for (int r = 0; r < 16; ++r) tile[(r + 16 * g) * 17 + j] = v[r];
    __syncthreads();
#pragma unroll
    for (int r = 0; r < 16; ++r) v[r] = tile[(g + 32 * r) * 17 + j];   // alpha

    // layer-1 high, alpha: q3-0
    bfly16<0>(v, c1h[3]); bfly16<1>(v, c1h[2]); bfly16<2>(v, c1h[1]); bfly16<3>(v, c1h[0]);

    {   // sign between layers
        unsigned lv = lvs[j];
        unsigned V = lv & 511u, sl = (lv >> NH) & 1u;
#pragma unroll
        for (int r = 0; r < 16; ++r) {
            int m = g + 32 * r;
            unsigned sgn = (sgh[m] ^ sl ^ (unsigned)__popc((unsigned)m & V)) & 1u;
            if (sgn) v[r] = -v[r];
        }
    }

    // layer-2 high, alpha: q3-0
    bfly16<0>(v, c2h[3]); bfly16<1>(v, c2h[2]); bfly16<2>(v, c2h[1]); bfly16<3>(v, c2h[0]);

    __syncthreads();
#pragma unroll
    for (int r = 0; r < 16; ++r) tile[(g + 32 * r) * 17 + j] = v[r];
    __syncthreads();
#pragma unroll
    for (int r = 0; r < 16; ++r) v[r] = tile[(r + 16 * g) * 17 + j];   // beta

    // layer-2 high, beta: q4 (shfl) + q8-5
    bflyx(v, c2h[4], 16, g & 1);
    bfly16<0>(v, c2h[8]); bfly16<1>(v, c2h[7]); bfly16<2>(v, c2h[6]); bfly16<3>(v, c2h[5]);

    float* op = state + rb + j;
#pragma unroll
    for (int r = 0; r < 16; ++r) op[(size_t)(r + 16 * g) * RS] = v[r];
}

// ---------------- kC: layer-2 low + probs + 22 expectation partials ----------
__global__ __launch_bounds__(512, 4) void kC(const float* state, const float* params,
                                             float* out) {
    __shared__ float chunk[8448];
    __shared__ float2 csl2[13];    // layer-2 low; csl2[qi] = qubit 9+qi
    const int h = blockIdx.x, t = threadIdx.x;

    if (t < 13) {
        float a = 0.5f * params[2 * NQ + 9 + t];
        csl2[t] = make_float2(cosf(a), sinf(a));
    }

    float v[16];
    const float* sp = state + (size_t)h * RS + t;                  // C mapping
#pragma unroll
    for (int r = 0; r < 16; ++r) v[r] = sp[512 * r];
    __syncthreads();   // csl2 ready

    // C stages: q12-9
    bfly16<0>(v, csl2[3]); bfly16<1>(v, csl2[2]); bfly16<2>(v, csl2[1]); bfly16<3>(v, csl2[0]);

    const int baseC = t + (t >> 5);
#pragma unroll
    for (int r = 0; r < 16; ++r) chunk[baseC + 528 * r] = v[r];
    __syncthreads();
    const int t5 = t & 31, th = t >> 5;
    const int baseB = t5 + 528 * th;
#pragma unroll
    for (int r = 0; r < 16; ++r) v[r] = chunk[baseB + 33 * r];     // mapping B

    // B stages: q16-13
    bfly16<0>(v, csl2[7]); bfly16<1>(v, csl2[6]); bfly16<2>(v, csl2[5]); bfly16<3>(v, csl2[4]);

    __syncthreads();
#pragma unroll
    for (int r = 0; r < 16; ++r) chunk[baseB + 33 * r] = v[r];
    __syncthreads();
    const int baseA = 16 * t + (t >> 1);
#pragma unroll
    for (int r = 0; r < 16; ++r) v[r] = chunk[baseA + r];          // mapping A

    // A stages: q21-18 in regs, q17 via lane bit 0
    bfly16<0>(v, csl2[12]); bfly16<1>(v, csl2[11]); bfly16<2>(v, csl2[10]); bfly16<3>(v, csl2[9]);
    bflyx(v, csl2[8], 1, t & 1);

    // probs + per-thread partials. A: l = r+16t -> reg bit k = qubit 21-k;
    // t bit i (0..8) = l bit 4+i = qubit 17-i.
#pragma unroll
    for (int r = 0; r < 16; ++r) v[r] = v[r] * v[r];
    float tot = 0.f;
#pragma unroll
    for (int r = 0; r < 16; ++r) tot += v[r];
    float s4[4];
#pragma unroll
    for (int k = 0; k < 4; ++k) {
        float a = 0.f;
#pragma unroll
        for (int r = 0; r < 16; ++r) a += ((r >> k) & 1) ? -v[r] : v[r];
        s4[k] = a;
    }

    __syncthreads();                     // chunk reads done before reuse
    chunk[t] = tot;
#pragma unroll
    for (int k = 0; k < 4; ++k) chunk[512 + k * 512 + t] = s4[k];
    __syncthreads();

    // stage 1: 176 threads, each sums 64 entries for (q, p)
    float* red = chunk + 2560;
    if (t < 176) {
        const int q = t >> 3, p = t & 7;
        float val = 0.f;
        if (q < 9) {
            for (int e = 0; e < 64; ++e) val += chunk[p * 64 + e];
        } else if (q < 18) {
            const int i = 17 - q;
            for (int e = 0; e < 64; ++e) {
                int tt = p * 64 + e;
                val += ((tt >> i) & 1) ? -chunk[tt] : chunk[tt];
            }
        } else {
            const int k = 21 - q;
            for (int e = 0; e < 64; ++e) val += chunk[512 + k * 512 + p * 64 + e];
        }
        red[q * 8 + p] = val;
    }
    __syncthreads();
    if (t < NQ) {
        float val = 0.f;
        for (int p = 0; p < 8; ++p) val += red[t * 8 + p];
        if (t < 9 && ((h >> (8 - t)) & 1)) val = -val;
        atomicAdd(&out[t], val);
    }
}

extern "C" void kernel_launch(void* const* d_in, const int* in_sizes, int n_in,
                              void* d_out, int out_size, void* d_ws, size_t ws_size,
                              hipStream_t stream) {
    const float* feat   = (const float*)d_in[0];   // 22
    const float* adj    = (const float*)d_in[1];   // 22*22
    const float* params = (const float*)d_in[2];   // 3*22
    float* out = (float*)d_out;                    // 22 f32

    float* state = (float*)d_ws;                   // 512*8224 floats ~ 16.05 MB

    kA<<<dim3(512), dim3(512), 0, stream>>>(state, feat, adj, params);
    kB<<<dim3(512), dim3(512), 0, stream>>>(state, adj, params, out);
    kC<<<dim3(512), dim3(512), 0, stream>>>(state, params, out);
}